// Round 5
// baseline (524.218 us; speedup 1.0000x reference)
//
#include <hip/hip_runtime.h>
#include <hip/hip_bf16.h>
#include <stdint.h>

#define B_ 8
#define M_ 2048
#define N_ 2048
#define D_ 1024

typedef __bf16 bf16x8 __attribute__((ext_vector_type(8)));
typedef float f32x4 __attribute__((ext_vector_type(4)));
typedef float f32x16 __attribute__((ext_vector_type(16)));
typedef uint16_t us4 __attribute__((ext_vector_type(4)));
typedef uint16_t us8 __attribute__((ext_vector_type(8)));

__device__ __forceinline__ uint16_t f2b(float f) {
    uint32_t u = __float_as_uint(f);
    return (uint16_t)((u + 0x7FFFu + ((u >> 16) & 1u)) >> 16);
}
__device__ __forceinline__ float b2f(uint16_t h) {
    return __uint_as_float(((uint32_t)h) << 16);
}

__device__ __forceinline__ void gld16(const uint16_t* g, const uint16_t* l) {
    __builtin_amdgcn_global_load_lds(
        (const __attribute__((address_space(1))) uint32_t*)g,
        (__attribute__((address_space(3))) uint32_t*)l,
        16, 0, 0);
}

// ---------------- split x,y into bf16 hi/lo ----------------
__global__ __launch_bounds__(256) void k_split(const float* __restrict__ x,
                                               const float* __restrict__ y,
                                               uint16_t* __restrict__ xh, uint16_t* __restrict__ xl,
                                               uint16_t* __restrict__ yh, uint16_t* __restrict__ yl) {
    const int i = (blockIdx.x * 256 + threadIdx.x) * 4;
    float4 vx = *(const float4*)(x + i);
    float4 vy = *(const float4*)(y + i);
    float fx[4] = {vx.x, vx.y, vx.z, vx.w};
    float fy[4] = {vy.x, vy.y, vy.z, vy.w};
    us4 hx, lx, hy, ly;
#pragma unroll
    for (int k = 0; k < 4; ++k) {
        uint16_t h = f2b(fx[k]);
        hx[k] = h; lx[k] = f2b(fx[k] - b2f(h));
        uint16_t g = f2b(fy[k]);
        hy[k] = g; ly[k] = f2b(fy[k] - b2f(g));
    }
    *(us4*)(xh + i) = hx;
    *(us4*)(xl + i) = lx;
    *(us4*)(yh + i) = hy;
    *(us4*)(yl + i) = ly;
}

// ---------------- GEMM1: e[b][m][n] = xh.yh^T + xh.yl^T + xl.yh^T ----------------
// r1/r3 data layout (256x256 tile, 8 waves 2Mx4N, BK=32, 4 tensor tiles per
// buffer, 2 LDS buffers = 128KB, verified 0-conflict granule swizzle) but with
// v_mfma_f32_32x32x16_bf16 (4x2 frags of 32x32 per wave): 2x FLOP per issued
// MFMA -> half the issue-port pressure (r0-r4 showed all 16x16 schedules cap
// at ~49% MfmaUtil with MfmaUtil+VALUBusy ~ issue-saturated) and a +15% higher
// measured pipe ceiling (2382 vs 2075 TF).
// A/B fragment layout (32x32x16): lane l holds row/col = l&31,
// k = (l>>5)*8 + e per K-chunk of 16; C/D (m74/m101-verified): col = lane&31,
// row = (reg&3) + 8*(reg>>2) + 4*(lane>>5).
// Epilogue: e tile + per-(row, 64-col-block) softmax partials (max, sum-exp).
__global__ __launch_bounds__(512, 2) void k_gemm1(const uint16_t* __restrict__ xh,
                                                  const uint16_t* __restrict__ xl,
                                                  const uint16_t* __restrict__ yh,
                                                  const uint16_t* __restrict__ yl,
                                                  float* __restrict__ e,
                                                  float* __restrict__ pmax,
                                                  float* __restrict__ psum) {
    const int b = blockIdx.z;
    const int m0 = blockIdx.x * 256;
    const int n0 = blockIdx.y * 256;
    __shared__ __align__(16) uint16_t lds[65536];  // 2 buf x 4 tiles x (256x32)

    const int tid = threadIdx.x;
    const int lane = tid & 63;
    const int wid = tid >> 6;             // 8 waves: 2 (m) x 4 (n)
    const int wm = (wid >> 2) * 128;
    const int wn = (wid & 3) * 64;
    const int l31 = lane & 31;
    const int hi = lane >> 5;
    const int swl = (l31 >> 1) & 3;       // (row>>1)&3 (frag/wave offsets are *32/*64)

    // staging (verbatim r1): chunk c -> tensor c>>1, rows (c&1)*128 + wid*16
    // + lane/4, granule lane&3 stored at pos ^((row>>1)&3)
    const int base_row = wid * 16 + (lane >> 2);
    const int gd8 = ((lane & 3) ^ ((lane >> 3) & 3)) * 8;
    const uint16_t* gp[4];
    gp[0] = xh + ((size_t)b * M_ + m0 + base_row) * D_ + gd8;
    gp[1] = xl + ((size_t)b * M_ + m0 + base_row) * D_ + gd8;
    gp[2] = yh + ((size_t)b * N_ + n0 + base_row) * D_ + gd8;
    gp[3] = yl + ((size_t)b * N_ + n0 + base_row) * D_ + gd8;
    const int ldsW = wid * 512;

    auto STAGE = [&](int dst, int ktn) {
#pragma unroll
        for (int c = 0; c < 8; ++c)
            gld16(gp[c >> 1] + (size_t)(c & 1) * (128 * D_) + ktn * 32,
                  &lds[dst + c * 4096 + ldsW]);
    };

    // fragment base offsets (granule term added per kc)
    const int abase = (wm + l31) * 32;            // xh tile @0, xl @+8192
    const int bbase = 16384 + (wn + l31) * 32;    // yh @16384, yl @+8192

    f32x16 acc[4][2];
#pragma unroll
    for (int i = 0; i < 4; ++i)
#pragma unroll
        for (int j = 0; j < 2; ++j)
#pragma unroll
            for (int r = 0; r < 16; ++r) acc[i][j][r] = 0.f;

    STAGE(0, 0);
    __syncthreads();

    for (int kt = 0; kt < D_ / 32; ++kt) {
        const int bo = (kt & 1) << 15;
        if (kt < D_ / 32 - 1) STAGE(bo ^ 32768, kt + 1);

#pragma unroll
        for (int kc = 0; kc < 2; ++kc) {
            const int g8 = ((hi + 2 * kc) ^ swl) * 8;
            bf16x8 ah[4], al[4], bh[2], bl[2];
#pragma unroll
            for (int j = 0; j < 2; ++j) {
                const int o = bo + bbase + j * 1024 + g8;
                bh[j] = *(const bf16x8*)&lds[o];
                bl[j] = *(const bf16x8*)&lds[o + 8192];
            }
#pragma unroll
            for (int i = 0; i < 4; ++i) {
                const int o = bo + abase + i * 1024 + g8;
                ah[i] = *(const bf16x8*)&lds[o];
                al[i] = *(const bf16x8*)&lds[o + 8192];
            }
            __builtin_amdgcn_s_setprio(1);
#pragma unroll
            for (int i = 0; i < 4; ++i)
#pragma unroll
                for (int j = 0; j < 2; ++j) {
                    acc[i][j] = __builtin_amdgcn_mfma_f32_32x32x16_bf16(ah[i], bh[j], acc[i][j], 0, 0, 0);
                    acc[i][j] = __builtin_amdgcn_mfma_f32_32x32x16_bf16(ah[i], bl[j], acc[i][j], 0, 0, 0);
                    acc[i][j] = __builtin_amdgcn_mfma_f32_32x32x16_bf16(al[i], bh[j], acc[i][j], 0, 0, 0);
                }
            __builtin_amdgcn_s_setprio(0);
        }
        __syncthreads();
    }

    // epilogue: e tile + per-(row, 64-col-block) softmax partials
    // C/D map: col = l31, row = (reg&3) + 8*(reg>>2) + 4*hi
    float* eb = e + (size_t)b * M_ * N_;
    const int grows = (int)gridDim.z * M_;
    const int growbase = b * M_ + m0 + wm;
    const int nb = (n0 + wn) >> 6;  // 0..31
    float* pm = pmax + (size_t)nb * grows + growbase;
    float* ps = psum + (size_t)nb * grows + growbase;

#pragma unroll
    for (int i = 0; i < 4; ++i) {
#pragma unroll
        for (int reg = 0; reg < 16; ++reg) {
            const float v0 = acc[i][0][reg], v1 = acc[i][1][reg];
            float mrow = fmaxf(v0, v1);
#pragma unroll
            for (int s = 1; s < 32; s <<= 1) mrow = fmaxf(mrow, __shfl_xor(mrow, s, 64));
            float srow_ = __expf(v0 - mrow) + __expf(v1 - mrow);
#pragma unroll
            for (int s = 1; s < 32; s <<= 1) srow_ += __shfl_xor(srow_, s, 64);
            const int lrow = i * 32 + (reg & 3) + 8 * (reg >> 2) + 4 * hi;
            if (l31 == 0) { pm[lrow] = mrow; ps[lrow] = srow_; }
            const size_t ebase = (size_t)(m0 + wm + lrow) * N_ + n0 + wn + l31;
            eb[ebase] = v0;
            eb[ebase + 32] = v1;
        }
    }
}

// ---------------- combine partials -> mx, inv ----------------
__global__ __launch_bounds__(256) void k_combine(const float* __restrict__ pmax,
                                                 const float* __restrict__ psum,
                                                 float* __restrict__ mx,
                                                 float* __restrict__ inv, int rows) {
    const int r = blockIdx.x * 256 + threadIdx.x;
    float m = -3.4e38f;
#pragma unroll
    for (int nb = 0; nb < 32; ++nb) m = fmaxf(m, pmax[(size_t)nb * rows + r]);
    float s = 0.f;
#pragma unroll
    for (int nb = 0; nb < 32; ++nb)
        s += psum[(size_t)nb * rows + r] * __expf(pmax[(size_t)nb * rows + r] - m);
    mx[r] = m;
    inv[r] = 1.0f / s;
}

// ---------------- transposed softmax: pT[b][n][m] = bf16(exp(e[b][m][n]-mx)*inv) ----------------
__global__ __launch_bounds__(256) void k_texp(const float* __restrict__ e,
                                              const float* __restrict__ mx,
                                              const float* __restrict__ inv,
                                              uint16_t* __restrict__ pT) {
    const int b = blockIdx.z, m0 = blockIdx.x * 64, n0 = blockIdx.y * 64;
    __shared__ float tile[64 * 65];
    const int t = threadIdx.x;
    const float* eb = e + (size_t)b * M_ * N_;
#pragma unroll
    for (int q = 0; q < 4; ++q) {
        const int row = q * 16 + (t >> 4);
        const int c4 = (t & 15) * 4;
        float4 v = *(const float4*)&eb[(size_t)(m0 + row) * N_ + n0 + c4];
        const float mv = mx[b * M_ + m0 + row];
        const float iv = inv[b * M_ + m0 + row];
        tile[row * 65 + c4 + 0] = __expf(v.x - mv) * iv;
        tile[row * 65 + c4 + 1] = __expf(v.y - mv) * iv;
        tile[row * 65 + c4 + 2] = __expf(v.z - mv) * iv;
        tile[row * 65 + c4 + 3] = __expf(v.w - mv) * iv;
    }
    __syncthreads();
    uint16_t* pb = pT + (size_t)b * N_ * M_;
#pragma unroll
    for (int q = 0; q < 2; ++q) {
        const int n = q * 32 + (t >> 3);
        const int mc = (t & 7) * 8;
        us8 o;
#pragma unroll
        for (int k = 0; k < 8; ++k) o[k] = f2b(tile[(mc + k) * 65 + n]);
        *(us8*)&pb[(size_t)(n0 + n) * M_ + m0 + mc] = o;
    }
}

// ---------------- transpose x: xt[b][d][m] = bf16(x[b][m][d]) ----------------
__global__ __launch_bounds__(256) void k_tx(const float* __restrict__ x,
                                            uint16_t* __restrict__ xt) {
    const int b = blockIdx.z, m0 = blockIdx.x * 64, d0 = blockIdx.y * 64;
    __shared__ float tile[64 * 65];
    const int t = threadIdx.x;
    const float* xb = x + (size_t)b * M_ * D_;
#pragma unroll
    for (int q = 0; q < 4; ++q) {
        const int row = q * 16 + (t >> 4);
        const int c4 = (t & 15) * 4;
        float4 v = *(const float4*)&xb[(size_t)(m0 + row) * D_ + d0 + c4];
        tile[row * 65 + c4 + 0] = v.x;
        tile[row * 65 + c4 + 1] = v.y;
        tile[row * 65 + c4 + 2] = v.z;
        tile[row * 65 + c4 + 3] = v.w;
    }
    __syncthreads();
    uint16_t* xtb = xt + (size_t)b * D_ * M_;
#pragma unroll
    for (int q = 0; q < 2; ++q) {
        const int d = q * 32 + (t >> 3);
        const int mc = (t & 7) * 8;
        us8 o;
#pragma unroll
        for (int k = 0; k < 8; ++k) o[k] = f2b(tile[(mc + k) * 65 + d]);
        *(us8*)&xtb[(size_t)(d0 + d) * M_ + m0 + mc] = o;
    }
}

// ---------------- GEMM2: out[b][n][d] = sum_m pT[b][n][m] * xt[b][d][m] ----------------
// Double-buffered (r4, confirmed -14us): next K-tile staged during compute;
// one __syncthreads per K-step.
__global__ __launch_bounds__(256) void k_gemm2(const uint16_t* __restrict__ pT,
                                               const uint16_t* __restrict__ xt,
                                               float* __restrict__ out) {
    const int b = blockIdx.z;
    const int n0 = blockIdx.x * 128;
    const int d0 = blockIdx.y * 128;
    __shared__ __align__(16) uint16_t lds[32768];  // 2 buf x 2 tiles x (128x64)

    const int tid = threadIdx.x;
    const int lane = tid & 63;
    const int wid = tid >> 6;
    const int wn = (wid & 1) * 64;
    const int wd = (wid >> 1) * 64;
    const int quad = lane >> 4;
    const int r16 = lane & 15;

    const uint16_t* srcA = pT + ((size_t)b * N_ + n0) * M_;
    const uint16_t* srcB = xt + ((size_t)b * D_ + d0) * M_;

    f32x4 acc[4][4];
#pragma unroll
    for (int i = 0; i < 4; ++i)
#pragma unroll
        for (int j = 0; j < 4; ++j) acc[i][j] = (f32x4){0.f, 0.f, 0.f, 0.f};

    auto STAGE = [&](int dst, int kt) {
#pragma unroll
        for (int c = 0; c < 8; ++c) {
            const int offbase = c * 2048 + wid * 512;
            const int tile = offbase >> 13;             // 8192 elems per tile
            const int o = (offbase & 8191) + lane * 8;
            const int row = o >> 6;                     // 64 elems per row
            const int gp = (o & 63) >> 3;               // granule position 0..7
            const int gd = gp ^ (row & 7);              // data granule (swizzle)
            const uint16_t* sp = tile ? srcB : srcA;
            gld16(sp + (size_t)row * M_ + kt * 64 + gd * 8, &lds[dst + offbase]);
        }
    };

    STAGE(0, 0);
    __syncthreads();

    for (int kt = 0; kt < M_ / 64; ++kt) {
        const int bo = (kt & 1) << 14;
        const int nbo = bo ^ 16384;
        if (kt < M_ / 64 - 1) STAGE(nbo, kt + 1);

#pragma unroll
        for (int h = 0; h < 2; ++h) {                   // two K=32 halves
            const int p = (h * 4 + quad) ^ (r16 & 7);   // swizzled granule pos
            bf16x8 a[4], bbr[4];
#pragma unroll
            for (int i = 0; i < 4; ++i) {
                a[i]   = *(const bf16x8*)&lds[bo + (wn + i * 16 + r16) * 64 + p * 8];
                bbr[i] = *(const bf16x8*)&lds[bo + 8192 + (wd + i * 16 + r16) * 64 + p * 8];
            }
#pragma unroll
            for (int i = 0; i < 4; ++i)
#pragma unroll
                for (int j = 0; j < 4; ++j)
                    acc[i][j] = __builtin_amdgcn_mfma_f32_16x16x32_bf16(a[i], bbr[j], acc[i][j], 0, 0, 0);
        }
        __syncthreads();
    }

    float* ob = out + (size_t)b * N_ * D_;
#pragma unroll
    for (int i = 0; i < 4; ++i) {
        const int rbase = n0 + wn + i * 16 + quad * 4;
#pragma unroll
        for (int j = 0; j < 4; ++j) {
            const int col = d0 + wd + j * 16 + r16;
#pragma unroll
            for (int r = 0; r < 4; ++r)
                ob[(size_t)(rbase + r) * D_ + col] = acc[i][j][r];
        }
    }
}

extern "C" void kernel_launch(void* const* d_in, const int* in_sizes, int n_in,
                              void* d_out, int out_size, void* d_ws, size_t ws_size,
                              hipStream_t stream) {
    const float* x = (const float*)d_in[0];
    const float* y = (const float*)d_in[1];
    float* out = (float*)d_out;
    char* ws = (char*)d_ws;

    // Per-chunk footprint (g batches), with overlays: exactly 32g MiB.
    //   [xh 4g][xl 4g][yh 4g][yl 4g][e 16g]
    // After gemm1 the split region is dead:
    //   stats (mx,inv) overlay xh; xt overlays xl; pT overlays yh+yl.
    const size_t MiB = 1024 * 1024;
    int g = 8;
    while (g > 1 && (size_t)g * 32 * MiB > ws_size) g >>= 1;
    if ((size_t)g * 32 * MiB > ws_size) return;  // ws too small: clean fail (diagnostic)

    const size_t T = (size_t)g * M_ * D_ * 2;  // one split tensor (4g MiB)
    uint16_t* xh = (uint16_t*)(ws + 0 * T);
    uint16_t* xl = (uint16_t*)(ws + 1 * T);
    uint16_t* yh = (uint16_t*)(ws + 2 * T);
    uint16_t* yl = (uint16_t*)(ws + 3 * T);
    float*    e  = (float*)(ws + 4 * T);
    float*    mx = (float*)(ws);               // overlays xh (dead after gemm1)
    float*    inv = mx + (size_t)g * M_;
    uint16_t* xt = xl;                          // overlays xl (dead after gemm1)
    uint16_t* pT = yh;                          // overlays yh+yl (dead after gemm1)

    // softmax partials live in the tail of d_out: d_out is dead until gemm2,
    // and only the LAST chunk's gemm2 covers the tail — after combine read it.
    const size_t pelems = (size_t)32 * g * M_;
    float* pmax = (float*)d_out + (size_t)B_ * N_ * D_ - 2 * pelems;
    float* psum = pmax + pelems;

    for (int c0 = 0; c0 < B_; c0 += g) {
        const float* xc = x + (size_t)c0 * M_ * D_;
        const float* yc = y + (size_t)c0 * N_ * D_;
        float* oc = out + (size_t)c0 * N_ * D_;

        hipLaunchKernelGGL(k_split, dim3((g * M_ * D_) / (256 * 4)), dim3(256), 0, stream,
                           xc, yc, xh, xl, yh, yl);
        hipLaunchKernelGGL(k_gemm1, dim3(M_ / 256, N_ / 256, g), dim3(512), 0, stream,
                           xh, xl, yh, yl, e, pmax, psum);
        hipLaunchKernelGGL(k_combine, dim3((g * M_) / 256), dim3(256), 0, stream,
                           pmax, psum, mx, inv, g * M_);
        hipLaunchKernelGGL(k_texp, dim3(M_ / 64, N_ / 64, g), dim3(256), 0, stream,
                           e, mx, inv, pT);
        hipLaunchKernelGGL(k_tx, dim3(M_ / 64, D_ / 64, g), dim3(256), 0, stream, xc, xt);
        hipLaunchKernelGGL(k_gemm2, dim3(N_ / 128, D_ / 128, g), dim3(256), 0, stream,
                           pT, xt, oc);
    }
}

// Round 6
// 467.602 us; speedup vs baseline: 1.1211x; 1.1211x over previous
//
#include <hip/hip_runtime.h>
#include <hip/hip_bf16.h>
#include <stdint.h>

#define B_ 8
#define M_ 2048
#define N_ 2048
#define D_ 1024

typedef __bf16 bf16x8 __attribute__((ext_vector_type(8)));
typedef float f32x4 __attribute__((ext_vector_type(4)));
typedef uint16_t us4 __attribute__((ext_vector_type(4)));
typedef uint16_t us8 __attribute__((ext_vector_type(8)));

__device__ __forceinline__ uint16_t f2b(float f) {
    uint32_t u = __float_as_uint(f);
    return (uint16_t)((u + 0x7FFFu + ((u >> 16) & 1u)) >> 16);
}
__device__ __forceinline__ float b2f(uint16_t h) {
    return __uint_as_float(((uint32_t)h) << 16);
}

__device__ __forceinline__ void gld16(const uint16_t* g, const uint16_t* l) {
    __builtin_amdgcn_global_load_lds(
        (const __attribute__((address_space(1))) uint32_t*)g,
        (__attribute__((address_space(3))) uint32_t*)l,
        16, 0, 0);
}

// ---------------- split x,y into bf16 hi/lo ----------------
__global__ __launch_bounds__(256) void k_split(const float* __restrict__ x,
                                               const float* __restrict__ y,
                                               uint16_t* __restrict__ xh, uint16_t* __restrict__ xl,
                                               uint16_t* __restrict__ yh, uint16_t* __restrict__ yl) {
    const int i = (blockIdx.x * 256 + threadIdx.x) * 4;
    float4 vx = *(const float4*)(x + i);
    float4 vy = *(const float4*)(y + i);
    float fx[4] = {vx.x, vx.y, vx.z, vx.w};
    float fy[4] = {vy.x, vy.y, vy.z, vy.w};
    us4 hx, lx, hy, ly;
#pragma unroll
    for (int k = 0; k < 4; ++k) {
        uint16_t h = f2b(fx[k]);
        hx[k] = h; lx[k] = f2b(fx[k] - b2f(h));
        uint16_t g = f2b(fy[k]);
        hy[k] = g; ly[k] = f2b(fy[k] - b2f(g));
    }
    *(us4*)(xh + i) = hx;
    *(us4*)(xl + i) = lx;
    *(us4*)(yh + i) = hy;
    *(us4*)(yl + i) = ly;
}

// ---------------- GEMM1: e[b][m][n] = xh.yh^T + xh.yl^T + xl.yh^T ----------------
// r3 structure verbatim (best measured: 186 us, MfmaUtil 49, 0 conflicts).
// 256x256 tile, 8 waves (2m x 4n, wave tile 128x64), BK=32, dbuf LDS 128KB,
// register-double-buffered A-fragments, 2-3 barriers/K-step, counted staging.
#define SBAR0 __builtin_amdgcn_sched_barrier(0)
#define LD8(off) (*(const bf16x8*)&lds[off])
#define RDB(bo)                                                        \
    _Pragma("unroll") for (int j = 0; j < 4; ++j) {                    \
        bh[j] = LD8((bo) + bbase + j * 512);                           \
        bl[j] = LD8((bo) + bbase + 8192 + j * 512);                    \
    }
#define RDA(H, L, bo, q)                                               \
    H[0] = LD8((bo) + abase + ((q)*2) * 512);                          \
    H[1] = LD8((bo) + abase + ((q)*2 + 1) * 512);                      \
    L[0] = LD8((bo) + abase + 8192 + ((q)*2) * 512);                   \
    L[1] = LD8((bo) + abase + 8192 + ((q)*2 + 1) * 512);
#define MMQ(H, L, q)                                                   \
    __builtin_amdgcn_s_setprio(1);                                     \
    _Pragma("unroll") for (int ii = 0; ii < 2; ++ii)                   \
    _Pragma("unroll") for (int j = 0; j < 4; ++j) {                    \
        acc[(q)*2 + ii][j] = __builtin_amdgcn_mfma_f32_16x16x32_bf16(  \
            H[ii], bh[j], acc[(q)*2 + ii][j], 0, 0, 0);                \
        acc[(q)*2 + ii][j] = __builtin_amdgcn_mfma_f32_16x16x32_bf16(  \
            H[ii], bl[j], acc[(q)*2 + ii][j], 0, 0, 0);                \
        acc[(q)*2 + ii][j] = __builtin_amdgcn_mfma_f32_16x16x32_bf16(  \
            L[ii], bh[j], acc[(q)*2 + ii][j], 0, 0, 0);                \
    }                                                                  \
    __builtin_amdgcn_s_setprio(0);

__global__ __launch_bounds__(512, 2) void k_gemm1(const uint16_t* __restrict__ xh,
                                                  const uint16_t* __restrict__ xl,
                                                  const uint16_t* __restrict__ yh,
                                                  const uint16_t* __restrict__ yl,
                                                  float* __restrict__ e,
                                                  float* __restrict__ pmax,
                                                  float* __restrict__ psum) {
    const int b = blockIdx.z;
    const int m0 = blockIdx.x * 256;
    const int n0 = blockIdx.y * 256;
    __shared__ __align__(16) uint16_t lds[65536];  // 2 buf x 4 tiles x (256x32)

    const int tid = threadIdx.x;
    const int lane = tid & 63;
    const int wid = tid >> 6;             // 8 waves: 2 (m) x 4 (n)
    const int wm = (wid >> 2) * 128;
    const int wn = (wid & 3) * 64;
    const int quad = lane >> 4;
    const int r16 = lane & 15;
    const int swz8 = (quad ^ ((r16 >> 1) & 3)) * 8;

    // staging: chunk c -> tensor c>>1, rows (c&1)*128 + wid*16 + lane/4,
    // granule lane&3 stored at pos ^((row>>1)&3)
    const int base_row = wid * 16 + (lane >> 2);
    const int gd8 = ((lane & 3) ^ ((lane >> 3) & 3)) * 8;
    const uint16_t* gp[4];
    gp[0] = xh + ((size_t)b * M_ + m0 + base_row) * D_ + gd8;
    gp[1] = xl + ((size_t)b * M_ + m0 + base_row) * D_ + gd8;
    gp[2] = yh + ((size_t)b * N_ + n0 + base_row) * D_ + gd8;
    gp[3] = yl + ((size_t)b * N_ + n0 + base_row) * D_ + gd8;
    const int ldsW = wid * 512;

    const int abase = (wm + r16) * 32 + swz8;          // xh tile @0, xl @+8192
    const int bbase = 16384 + (wn + r16) * 32 + swz8;  // yh @16384, yl @+8192

    auto STAGE = [&](int dst, int ktn) {
#pragma unroll
        for (int c = 0; c < 8; ++c)
            gld16(gp[c >> 1] + (size_t)(c & 1) * (128 * D_) + ktn * 32,
                  &lds[dst + c * 4096 + ldsW]);
    };

    f32x4 acc[8][4];
#pragma unroll
    for (int i = 0; i < 8; ++i)
#pragma unroll
        for (int j = 0; j < 4; ++j) acc[i][j] = (f32x4){0.f, 0.f, 0.f, 0.f};

    bf16x8 bh[4], bl[4];
    bf16x8 a0h[2], a0l[2];   // register set 0 (itile pairs 0,2 and next-tile 0)
    bf16x8 a1h[2], a1l[2];   // register set 1 (itile pairs 1,3)

    // prologue: stage tile 0, publish, prime B + pair0 into set 0
    STAGE(0, 0);
    asm volatile("s_waitcnt vmcnt(0)" ::: "memory");
    SBAR0; __builtin_amdgcn_s_barrier(); SBAR0;
    RDB(0); RDA(a0h, a0l, 0, 0);

    for (int t = 0; t < 32; ++t) {
        const int bo = (t & 1) << 15;
        const int nbo = bo ^ 32768;
        const bool more = t < 31;

        // W0: stage tile t+1 into buf', read pair1 -> set1, MFMA pair0 (set0)
        if (more) STAGE(nbo, t + 1);
        RDA(a1h, a1l, bo, 1);
        SBAR0;
        MMQ(a0h, a0l, 0);
        SBAR0;

        // W1: read pair2 -> set0, MFMA pair1 (set1)
        RDA(a0h, a0l, bo, 2);
        SBAR0;
        MMQ(a1h, a1l, 1);
        SBAR0;

        // W2: read pair3 -> set1, MFMA pair2 (set0)
        RDA(a1h, a1l, bo, 3);
        SBAR0;
        MMQ(a0h, a0l, 2);
        SBAR0;

        // boundary: buf' staged ~2 windows ago -> vmcnt(0) normally free
        asm volatile("s_waitcnt vmcnt(0)" ::: "memory");
        SBAR0; __builtin_amdgcn_s_barrier(); SBAR0;

        // W3: read next tile's pair0 -> set0, MFMA pair3 (set1), then next B
        if (more) { RDA(a0h, a0l, nbo, 0); }
        SBAR0;
        MMQ(a1h, a1l, 3);
        SBAR0;
        if (more) {
            RDB(nbo);                       // after last use of bh/bl(t)
            SBAR0; __builtin_amdgcn_s_barrier(); SBAR0;  // tile-start: buf reads done
        }
    }

    // epilogue: e tile + per-(row, 64-col-block) softmax partials
    float* eb = e + (size_t)b * M_ * N_;
    const int grows = (int)gridDim.z * M_;
    const int growbase = b * M_ + m0 + wm;
    const int nb = (n0 + wn) >> 6;  // 0..31
    float* pm = pmax + (size_t)nb * grows + growbase;
    float* ps = psum + (size_t)nb * grows + growbase;

#pragma unroll
    for (int i = 0; i < 8; ++i) {
#pragma unroll
        for (int r = 0; r < 4; ++r) {
            const float v0 = acc[i][0][r], v1 = acc[i][1][r];
            const float v2 = acc[i][2][r], v3 = acc[i][3][r];
            float mrow = fmaxf(fmaxf(v0, v1), fmaxf(v2, v3));
#pragma unroll
            for (int s = 1; s < 16; s <<= 1) mrow = fmaxf(mrow, __shfl_xor(mrow, s, 64));
            float srow_ = __expf(v0 - mrow) + __expf(v1 - mrow)
                        + __expf(v2 - mrow) + __expf(v3 - mrow);
#pragma unroll
            for (int s = 1; s < 16; s <<= 1) srow_ += __shfl_xor(srow_, s, 64);
            const int lrow = i * 16 + quad * 4 + r;
            if (r16 == 0) { pm[lrow] = mrow; ps[lrow] = srow_; }
            const size_t ebase = (size_t)(m0 + wm + lrow) * N_ + n0 + wn + r16;
#pragma unroll
            for (int j = 0; j < 4; ++j) eb[ebase + j * 16] = acc[i][j][r];
        }
    }
}

// ---------------- combine partials -> mx, inv ----------------
__global__ __launch_bounds__(256) void k_combine(const float* __restrict__ pmax,
                                                 const float* __restrict__ psum,
                                                 float* __restrict__ mx,
                                                 float* __restrict__ inv, int rows) {
    const int r = blockIdx.x * 256 + threadIdx.x;
    float m = -3.4e38f;
#pragma unroll
    for (int nb = 0; nb < 32; ++nb) m = fmaxf(m, pmax[(size_t)nb * rows + r]);
    float s = 0.f;
#pragma unroll
    for (int nb = 0; nb < 32; ++nb)
        s += psum[(size_t)nb * rows + r] * __expf(pmax[(size_t)nb * rows + r] - m);
    mx[r] = m;
    inv[r] = 1.0f / s;
}

// ---------------- transposed softmax: pT[b][n][m] = bf16(exp(e[b][m][n]-mx)*inv) ----------------
__global__ __launch_bounds__(256) void k_texp(const float* __restrict__ e,
                                              const float* __restrict__ mx,
                                              const float* __restrict__ inv,
                                              uint16_t* __restrict__ pT) {
    const int b = blockIdx.z, m0 = blockIdx.x * 64, n0 = blockIdx.y * 64;
    __shared__ float tile[64 * 65];
    const int t = threadIdx.x;
    const float* eb = e + (size_t)b * M_ * N_;
#pragma unroll
    for (int q = 0; q < 4; ++q) {
        const int row = q * 16 + (t >> 4);
        const int c4 = (t & 15) * 4;
        float4 v = *(const float4*)&eb[(size_t)(m0 + row) * N_ + n0 + c4];
        const float mv = mx[b * M_ + m0 + row];
        const float iv = inv[b * M_ + m0 + row];
        tile[row * 65 + c4 + 0] = __expf(v.x - mv) * iv;
        tile[row * 65 + c4 + 1] = __expf(v.y - mv) * iv;
        tile[row * 65 + c4 + 2] = __expf(v.z - mv) * iv;
        tile[row * 65 + c4 + 3] = __expf(v.w - mv) * iv;
    }
    __syncthreads();
    uint16_t* pb = pT + (size_t)b * N_ * M_;
#pragma unroll
    for (int q = 0; q < 2; ++q) {
        const int n = q * 32 + (t >> 3);
        const int mc = (t & 7) * 8;
        us8 o;
#pragma unroll
        for (int k = 0; k < 8; ++k) o[k] = f2b(tile[(mc + k) * 65 + n]);
        *(us8*)&pb[(size_t)(n0 + n) * M_ + m0 + mc] = o;
    }
}

// ---------------- transpose xh: xt[b][d][m] = xh[b][m][d] ----------------
// Now reads xh (bf16, 32 MiB) instead of x (f32, 64 MiB): xt is definitionally
// the transpose of xh, and f2b(b2f(h)) == h, so output is bit-identical.
__global__ __launch_bounds__(256) void k_tx(const uint16_t* __restrict__ xh,
                                            uint16_t* __restrict__ xt) {
    const int b = blockIdx.z, m0 = blockIdx.x * 64, d0 = blockIdx.y * 64;
    __shared__ float tile[64 * 65];
    const int t = threadIdx.x;
    const uint16_t* xb = xh + (size_t)b * M_ * D_;
#pragma unroll
    for (int q = 0; q < 2; ++q) {
        const int row = q * 32 + (t >> 3);
        const int c8 = (t & 7) * 8;
        us8 v = *(const us8*)&xb[(size_t)(m0 + row) * D_ + d0 + c8];
#pragma unroll
        for (int k = 0; k < 8; ++k) tile[row * 65 + c8 + k] = b2f(v[k]);
    }
    __syncthreads();
    uint16_t* xtb = xt + (size_t)b * D_ * M_;
#pragma unroll
    for (int q = 0; q < 2; ++q) {
        const int d = q * 32 + (t >> 3);
        const int mc = (t & 7) * 8;
        us8 o;
#pragma unroll
        for (int k = 0; k < 8; ++k) o[k] = f2b(tile[(mc + k) * 65 + d]);
        *(us8*)&xtb[(size_t)(d0 + d) * M_ + m0 + mc] = o;
    }
}

// ---------------- GEMM2: out[b][n][d] = sum_m pT[b][n][m] * xt[b][d][m] ----------------
// Double-buffered (r4/r5, confirmed ~-13us): next K-tile staged during
// compute; one __syncthreads per K-step.
__global__ __launch_bounds__(256) void k_gemm2(const uint16_t* __restrict__ pT,
                                               const uint16_t* __restrict__ xt,
                                               float* __restrict__ out) {
    const int b = blockIdx.z;
    const int n0 = blockIdx.x * 128;
    const int d0 = blockIdx.y * 128;
    __shared__ __align__(16) uint16_t lds[32768];  // 2 buf x 2 tiles x (128x64)

    const int tid = threadIdx.x;
    const int lane = tid & 63;
    const int wid = tid >> 6;
    const int wn = (wid & 1) * 64;
    const int wd = (wid >> 1) * 64;
    const int quad = lane >> 4;
    const int r16 = lane & 15;

    const uint16_t* srcA = pT + ((size_t)b * N_ + n0) * M_;
    const uint16_t* srcB = xt + ((size_t)b * D_ + d0) * M_;

    f32x4 acc[4][4];
#pragma unroll
    for (int i = 0; i < 4; ++i)
#pragma unroll
        for (int j = 0; j < 4; ++j) acc[i][j] = (f32x4){0.f, 0.f, 0.f, 0.f};

    auto STAGE = [&](int dst, int kt) {
#pragma unroll
        for (int c = 0; c < 8; ++c) {
            const int offbase = c * 2048 + wid * 512;
            const int tile = offbase >> 13;             // 8192 elems per tile
            const int o = (offbase & 8191) + lane * 8;
            const int row = o >> 6;                     // 64 elems per row
            const int gp = (o & 63) >> 3;               // granule position 0..7
            const int gd = gp ^ (row & 7);              // data granule (swizzle)
            const uint16_t* sp = tile ? srcB : srcA;
            gld16(sp + (size_t)row * M_ + kt * 64 + gd * 8, &lds[dst + offbase]);
        }
    };

    STAGE(0, 0);
    __syncthreads();

    for (int kt = 0; kt < M_ / 64; ++kt) {
        const int bo = (kt & 1) << 14;
        const int nbo = bo ^ 16384;
        if (kt < M_ / 64 - 1) STAGE(nbo, kt + 1);

#pragma unroll
        for (int h = 0; h < 2; ++h) {                   // two K=32 halves
            const int p = (h * 4 + quad) ^ (r16 & 7);   // swizzled granule pos
            bf16x8 a[4], bbr[4];
#pragma unroll
            for (int i = 0; i < 4; ++i) {
                a[i]   = *(const bf16x8*)&lds[bo + (wn + i * 16 + r16) * 64 + p * 8];
                bbr[i] = *(const bf16x8*)&lds[bo + 8192 + (wd + i * 16 + r16) * 64 + p * 8];
            }
#pragma unroll
            for (int i = 0; i < 4; ++i)
#pragma unroll
                for (int j = 0; j < 4; ++j)
                    acc[i][j] = __builtin_amdgcn_mfma_f32_16x16x32_bf16(a[i], bbr[j], acc[i][j], 0, 0, 0);
        }
        __syncthreads();
    }

    float* ob = out + (size_t)b * N_ * D_;
#pragma unroll
    for (int i = 0; i < 4; ++i) {
        const int rbase = n0 + wn + i * 16 + quad * 4;
#pragma unroll
        for (int j = 0; j < 4; ++j) {
            const int col = d0 + wd + j * 16 + r16;
#pragma unroll
            for (int r = 0; r < 4; ++r)
                ob[(size_t)(rbase + r) * D_ + col] = acc[i][j][r];
        }
    }
}

extern "C" void kernel_launch(void* const* d_in, const int* in_sizes, int n_in,
                              void* d_out, int out_size, void* d_ws, size_t ws_size,
                              hipStream_t stream) {
    const float* x = (const float*)d_in[0];
    const float* y = (const float*)d_in[1];
    float* out = (float*)d_out;
    char* ws = (char*)d_ws;

    // Per-chunk footprint (g batches), with overlays: exactly 32g MiB.
    //   [xh 4g][xl 4g][yh 4g][yl 4g][e 16g]
    // After gemm1: xt overlays xl (dead); pT overlays yh+yl (dead).
    // xh stays ALIVE through k_tx (which reads it) -> stats moved to d_out tail.
    const size_t MiB = 1024 * 1024;
    int g = 8;
    while (g > 1 && (size_t)g * 32 * MiB > ws_size) g >>= 1;
    if ((size_t)g * 32 * MiB > ws_size) return;  // ws too small: clean fail (diagnostic)

    const size_t T = (size_t)g * M_ * D_ * 2;  // one split tensor (4g MiB)
    uint16_t* xh = (uint16_t*)(ws + 0 * T);
    uint16_t* xl = (uint16_t*)(ws + 1 * T);
    uint16_t* yh = (uint16_t*)(ws + 2 * T);
    uint16_t* yl = (uint16_t*)(ws + 3 * T);
    float*    e  = (float*)(ws + 4 * T);
    uint16_t* xt = xl;                          // overlays xl (dead after gemm1)
    uint16_t* pT = yh;                          // overlays yh+yl (dead after gemm1)

    // Partials + stats live in the tail of d_out: d_out is dead until gemm2,
    // and only the SAME chunk's gemm2 (after texp consumed them) covers the
    // tail; earlier chunks' gemm2 never touch it.
    const size_t pelems = (size_t)32 * g * M_;
    float* dtail = (float*)d_out + (size_t)B_ * N_ * D_;
    float* pmax = dtail - 2 * pelems;
    float* psum = pmax + pelems;
    float* mx   = dtail - 2 * pelems - 2 * (size_t)g * M_;
    float* inv  = mx + (size_t)g * M_;

    for (int c0 = 0; c0 < B_; c0 += g) {
        const float* xc = x + (size_t)c0 * M_ * D_;
        const float* yc = y + (size_t)c0 * N_ * D_;
        float* oc = out + (size_t)c0 * N_ * D_;

        hipLaunchKernelGGL(k_split, dim3((g * M_ * D_) / (256 * 4)), dim3(256), 0, stream,
                           xc, yc, xh, xl, yh, yl);
        hipLaunchKernelGGL(k_gemm1, dim3(M_ / 256, N_ / 256, g), dim3(512), 0, stream,
                           xh, xl, yh, yl, e, pmax, psum);
        hipLaunchKernelGGL(k_combine, dim3((g * M_) / 256), dim3(256), 0, stream,
                           pmax, psum, mx, inv, g * M_);
        hipLaunchKernelGGL(k_texp, dim3(M_ / 64, N_ / 64, g), dim3(256), 0, stream,
                           e, mx, inv, pT);
        hipLaunchKernelGGL(k_tx, dim3(M_ / 64, D_ / 64, g), dim3(256), 0, stream, xh, xt);
        hipLaunchKernelGGL(k_gemm2, dim3(N_ / 128, D_ / 128, g), dim3(256), 0, stream,
                           pT, xt, oc);
    }
}

// Round 7
// 458.848 us; speedup vs baseline: 1.1425x; 1.0191x over previous
//
#include <hip/hip_runtime.h>
#include <hip/hip_bf16.h>
#include <stdint.h>

#define B_ 8
#define M_ 2048
#define N_ 2048
#define D_ 1024

typedef __bf16 bf16x8 __attribute__((ext_vector_type(8)));
typedef float f32x4 __attribute__((ext_vector_type(4)));
typedef uint16_t us4 __attribute__((ext_vector_type(4)));
typedef uint16_t us8 __attribute__((ext_vector_type(8)));

__device__ __forceinline__ uint16_t f2b(float f) {
    uint32_t u = __float_as_uint(f);
    return (uint16_t)((u + 0x7FFFu + ((u >> 16) & 1u)) >> 16);
}
__device__ __forceinline__ float b2f(uint16_t h) {
    return __uint_as_float(((uint32_t)h) << 16);
}

__device__ __forceinline__ void gld16(const uint16_t* g, const uint16_t* l) {
    __builtin_amdgcn_global_load_lds(
        (const __attribute__((address_space(1))) uint32_t*)g,
        (__attribute__((address_space(3))) uint32_t*)l,
        16, 0, 0);
}

// ---------------- split x,y into bf16 hi/lo ----------------
__global__ __launch_bounds__(256) void k_split(const float* __restrict__ x,
                                               const float* __restrict__ y,
                                               uint16_t* __restrict__ xh, uint16_t* __restrict__ xl,
                                               uint16_t* __restrict__ yh, uint16_t* __restrict__ yl) {
    const int i = (blockIdx.x * 256 + threadIdx.x) * 4;
    float4 vx = *(const float4*)(x + i);
    float4 vy = *(const float4*)(y + i);
    float fx[4] = {vx.x, vx.y, vx.z, vx.w};
    float fy[4] = {vy.x, vy.y, vy.z, vy.w};
    us4 hx, lx, hy, ly;
#pragma unroll
    for (int k = 0; k < 4; ++k) {
        uint16_t h = f2b(fx[k]);
        hx[k] = h; lx[k] = f2b(fx[k] - b2f(h));
        uint16_t g = f2b(fy[k]);
        hy[k] = g; ly[k] = f2b(fy[k] - b2f(g));
    }
    *(us4*)(xh + i) = hx;
    *(us4*)(xl + i) = lx;
    *(us4*)(yh + i) = hy;
    *(us4*)(yl + i) = ly;
}

// ---------------- GEMM1: e[b][m][n] = xh.yh^T + xh.yl^T + xl.yh^T ----------------
// r3 structure verbatim (best measured: 186 us, MfmaUtil 49-51, 0 conflicts).
#define SBAR0 __builtin_amdgcn_sched_barrier(0)
#define LD8(off) (*(const bf16x8*)&lds[off])
#define RDB(bo)                                                        \
    _Pragma("unroll") for (int j = 0; j < 4; ++j) {                    \
        bh[j] = LD8((bo) + bbase + j * 512);                           \
        bl[j] = LD8((bo) + bbase + 8192 + j * 512);                    \
    }
#define RDA(H, L, bo, q)                                               \
    H[0] = LD8((bo) + abase + ((q)*2) * 512);                          \
    H[1] = LD8((bo) + abase + ((q)*2 + 1) * 512);                      \
    L[0] = LD8((bo) + abase + 8192 + ((q)*2) * 512);                   \
    L[1] = LD8((bo) + abase + 8192 + ((q)*2 + 1) * 512);
#define MMQ(H, L, q)                                                   \
    __builtin_amdgcn_s_setprio(1);                                     \
    _Pragma("unroll") for (int ii = 0; ii < 2; ++ii)                   \
    _Pragma("unroll") for (int j = 0; j < 4; ++j) {                    \
        acc[(q)*2 + ii][j] = __builtin_amdgcn_mfma_f32_16x16x32_bf16(  \
            H[ii], bh[j], acc[(q)*2 + ii][j], 0, 0, 0);                \
        acc[(q)*2 + ii][j] = __builtin_amdgcn_mfma_f32_16x16x32_bf16(  \
            H[ii], bl[j], acc[(q)*2 + ii][j], 0, 0, 0);                \
        acc[(q)*2 + ii][j] = __builtin_amdgcn_mfma_f32_16x16x32_bf16(  \
            L[ii], bh[j], acc[(q)*2 + ii][j], 0, 0, 0);                \
    }                                                                  \
    __builtin_amdgcn_s_setprio(0);

__global__ __launch_bounds__(512, 2) void k_gemm1(const uint16_t* __restrict__ xh,
                                                  const uint16_t* __restrict__ xl,
                                                  const uint16_t* __restrict__ yh,
                                                  const uint16_t* __restrict__ yl,
                                                  float* __restrict__ e,
                                                  float* __restrict__ pmax,
                                                  float* __restrict__ psum) {
    const int b = blockIdx.z;
    const int m0 = blockIdx.x * 256;
    const int n0 = blockIdx.y * 256;
    __shared__ __align__(16) uint16_t lds[65536];  // 2 buf x 4 tiles x (256x32)

    const int tid = threadIdx.x;
    const int lane = tid & 63;
    const int wid = tid >> 6;             // 8 waves: 2 (m) x 4 (n)
    const int wm = (wid >> 2) * 128;
    const int wn = (wid & 3) * 64;
    const int quad = lane >> 4;
    const int r16 = lane & 15;
    const int swz8 = (quad ^ ((r16 >> 1) & 3)) * 8;

    const int base_row = wid * 16 + (lane >> 2);
    const int gd8 = ((lane & 3) ^ ((lane >> 3) & 3)) * 8;
    const uint16_t* gp[4];
    gp[0] = xh + ((size_t)b * M_ + m0 + base_row) * D_ + gd8;
    gp[1] = xl + ((size_t)b * M_ + m0 + base_row) * D_ + gd8;
    gp[2] = yh + ((size_t)b * N_ + n0 + base_row) * D_ + gd8;
    gp[3] = yl + ((size_t)b * N_ + n0 + base_row) * D_ + gd8;
    const int ldsW = wid * 512;

    const int abase = (wm + r16) * 32 + swz8;          // xh tile @0, xl @+8192
    const int bbase = 16384 + (wn + r16) * 32 + swz8;  // yh @16384, yl @+8192

    auto STAGE = [&](int dst, int ktn) {
#pragma unroll
        for (int c = 0; c < 8; ++c)
            gld16(gp[c >> 1] + (size_t)(c & 1) * (128 * D_) + ktn * 32,
                  &lds[dst + c * 4096 + ldsW]);
    };

    f32x4 acc[8][4];
#pragma unroll
    for (int i = 0; i < 8; ++i)
#pragma unroll
        for (int j = 0; j < 4; ++j) acc[i][j] = (f32x4){0.f, 0.f, 0.f, 0.f};

    bf16x8 bh[4], bl[4];
    bf16x8 a0h[2], a0l[2];
    bf16x8 a1h[2], a1l[2];

    STAGE(0, 0);
    asm volatile("s_waitcnt vmcnt(0)" ::: "memory");
    SBAR0; __builtin_amdgcn_s_barrier(); SBAR0;
    RDB(0); RDA(a0h, a0l, 0, 0);

    for (int t = 0; t < 32; ++t) {
        const int bo = (t & 1) << 15;
        const int nbo = bo ^ 32768;
        const bool more = t < 31;

        if (more) STAGE(nbo, t + 1);
        RDA(a1h, a1l, bo, 1);
        SBAR0;
        MMQ(a0h, a0l, 0);
        SBAR0;

        RDA(a0h, a0l, bo, 2);
        SBAR0;
        MMQ(a1h, a1l, 1);
        SBAR0;

        RDA(a1h, a1l, bo, 3);
        SBAR0;
        MMQ(a0h, a0l, 2);
        SBAR0;

        asm volatile("s_waitcnt vmcnt(0)" ::: "memory");
        SBAR0; __builtin_amdgcn_s_barrier(); SBAR0;

        if (more) { RDA(a0h, a0l, nbo, 0); }
        SBAR0;
        MMQ(a1h, a1l, 3);
        SBAR0;
        if (more) {
            RDB(nbo);
            SBAR0; __builtin_amdgcn_s_barrier(); SBAR0;
        }
    }

    // epilogue: e tile + per-(row, 64-col-block) softmax partials
    float* eb = e + (size_t)b * M_ * N_;
    const int grows = (int)gridDim.z * M_;
    const int growbase = b * M_ + m0 + wm;
    const int nb = (n0 + wn) >> 6;  // 0..31
    float* pm = pmax + (size_t)nb * grows + growbase;
    float* ps = psum + (size_t)nb * grows + growbase;

#pragma unroll
    for (int i = 0; i < 8; ++i) {
#pragma unroll
        for (int r = 0; r < 4; ++r) {
            const float v0 = acc[i][0][r], v1 = acc[i][1][r];
            const float v2 = acc[i][2][r], v3 = acc[i][3][r];
            float mrow = fmaxf(fmaxf(v0, v1), fmaxf(v2, v3));
#pragma unroll
            for (int s = 1; s < 16; s <<= 1) mrow = fmaxf(mrow, __shfl_xor(mrow, s, 64));
            float srow_ = __expf(v0 - mrow) + __expf(v1 - mrow)
                        + __expf(v2 - mrow) + __expf(v3 - mrow);
#pragma unroll
            for (int s = 1; s < 16; s <<= 1) srow_ += __shfl_xor(srow_, s, 64);
            const int lrow = i * 16 + quad * 4 + r;
            if (r16 == 0) { pm[lrow] = mrow; ps[lrow] = srow_; }
            const size_t ebase = (size_t)(m0 + wm + lrow) * N_ + n0 + wn + r16;
#pragma unroll
            for (int j = 0; j < 4; ++j) eb[ebase + j * 16] = acc[i][j][r];
        }
    }
}

// ---------------- combine partials -> mx, inv ----------------
__global__ __launch_bounds__(256) void k_combine(const float* __restrict__ pmax,
                                                 const float* __restrict__ psum,
                                                 float* __restrict__ mx,
                                                 float* __restrict__ inv, int rows) {
    const int r = blockIdx.x * 256 + threadIdx.x;
    float m = -3.4e38f;
#pragma unroll
    for (int nb = 0; nb < 32; ++nb) m = fmaxf(m, pmax[(size_t)nb * rows + r]);
    float s = 0.f;
#pragma unroll
    for (int nb = 0; nb < 32; ++nb)
        s += psum[(size_t)nb * rows + r] * __expf(pmax[(size_t)nb * rows + r] - m);
    mx[r] = m;
    inv[r] = 1.0f / s;
}

// ---------------- transposed softmax: pT[b][n][m] = bf16(exp(e[b][m][n]-mx)*inv) ----------------
__global__ __launch_bounds__(256) void k_texp(const float* __restrict__ e,
                                              const float* __restrict__ mx,
                                              const float* __restrict__ inv,
                                              uint16_t* __restrict__ pT) {
    const int b = blockIdx.z, m0 = blockIdx.x * 64, n0 = blockIdx.y * 64;
    __shared__ float tile[64 * 65];
    const int t = threadIdx.x;
    const float* eb = e + (size_t)b * M_ * N_;
#pragma unroll
    for (int q = 0; q < 4; ++q) {
        const int row = q * 16 + (t >> 4);
        const int c4 = (t & 15) * 4;
        float4 v = *(const float4*)&eb[(size_t)(m0 + row) * N_ + n0 + c4];
        const float mv = mx[b * M_ + m0 + row];
        const float iv = inv[b * M_ + m0 + row];
        tile[row * 65 + c4 + 0] = __expf(v.x - mv) * iv;
        tile[row * 65 + c4 + 1] = __expf(v.y - mv) * iv;
        tile[row * 65 + c4 + 2] = __expf(v.z - mv) * iv;
        tile[row * 65 + c4 + 3] = __expf(v.w - mv) * iv;
    }
    __syncthreads();
    uint16_t* pb = pT + (size_t)b * N_ * M_;
#pragma unroll
    for (int q = 0; q < 2; ++q) {
        const int n = q * 32 + (t >> 3);
        const int mc = (t & 7) * 8;
        us8 o;
#pragma unroll
        for (int k = 0; k < 8; ++k) o[k] = f2b(tile[(mc + k) * 65 + n]);
        *(us8*)&pb[(size_t)(n0 + n) * M_ + m0 + mc] = o;
    }
}

// ---------------- transpose xh: xt[b][d][m] = xh[b][m][d] ----------------
__global__ __launch_bounds__(256) void k_tx(const uint16_t* __restrict__ xh,
                                            uint16_t* __restrict__ xt) {
    const int b = blockIdx.z, m0 = blockIdx.x * 64, d0 = blockIdx.y * 64;
    __shared__ float tile[64 * 65];
    const int t = threadIdx.x;
    const uint16_t* xb = xh + (size_t)b * M_ * D_;
#pragma unroll
    for (int q = 0; q < 2; ++q) {
        const int row = q * 32 + (t >> 3);
        const int c8 = (t & 7) * 8;
        us8 v = *(const us8*)&xb[(size_t)(m0 + row) * D_ + d0 + c8];
#pragma unroll
        for (int k = 0; k < 8; ++k) tile[row * 65 + c8 + k] = b2f(v[k]);
    }
    __syncthreads();
    uint16_t* xtb = xt + (size_t)b * D_ * M_;
#pragma unroll
    for (int q = 0; q < 2; ++q) {
        const int d = q * 32 + (t >> 3);
        const int mc = (t & 7) * 8;
        us8 o;
#pragma unroll
        for (int k = 0; k < 8; ++k) o[k] = f2b(tile[(mc + k) * 65 + d]);
        *(us8*)&xtb[(size_t)(d0 + d) * M_ + m0 + mc] = o;
    }
}

// ---------------- GEMM2: out[b][n][d] = sum_m pT[b][n][m] * xt[b][d][m] ----------------
// 256x256 tile, 512 thr, 8 waves (wave tile 128n x 64d), BK=64, dbuf 128KB.
// r6 budget analysis: 128^2-tile gemm2 streamed ~1 GiB of pT/xt slabs through
// L2/L3 (16x8 grid x 1MB) -> ~190us inferred, ~360 TF. 256^2 halves slab
// traffic and doubles per-block intensity; grid 8x4x8 = 256 blocks = 1/CU.
// K-loop pattern and the measured-0-conflict granule swizzle g^(row&7) are
// the verified r4/r5 ones; per-output K-accumulation order unchanged ->
// bit-identical out.
__global__ __launch_bounds__(512, 2) void k_gemm2(const uint16_t* __restrict__ pT,
                                                  const uint16_t* __restrict__ xt,
                                                  float* __restrict__ out) {
    const int b = blockIdx.z;
    const int n0 = blockIdx.x * 256;
    const int d0 = blockIdx.y * 256;
    __shared__ __align__(16) uint16_t lds[65536];  // 2 buf x (A 32KB + B 32KB)

    const int tid = threadIdx.x;
    const int lane = tid & 63;
    const int wid = tid >> 6;             // 8 waves: 2 (n) x 4 (d)
    const int wn = (wid >> 2) * 128;
    const int wd = (wid & 3) * 64;
    const int quad = lane >> 4;
    const int r16 = lane & 15;

    const uint16_t* srcA = pT + ((size_t)b * N_ + n0) * M_;
    const uint16_t* srcB = xt + ((size_t)b * D_ + d0) * M_;

    // staging: K-step = A[256][64] + B[256][64] = 64KB = 8 chunks x 8KB.
    // chunk c: tensor c<4?A:B, rows (c&3)*64 + tid>>3; granule tid&7 stored
    // at pos p -> source granule gd = (tid&7) ^ (row&7), row&7 = (tid>>3)&7.
    const int srow = tid >> 3;
    const int gd8 = ((tid & 7) ^ (srow & 7)) * 8;
    const int ldsW = wid * 512;

    auto STAGE = [&](int dst, int kt) {
#pragma unroll
        for (int c = 0; c < 8; ++c) {
            const uint16_t* sp = (c < 4) ? srcA : srcB;
            const int r = (c & 3) * 64 + srow;
            gld16(sp + (size_t)r * M_ + kt * 64 + gd8,
                  &lds[dst + ((c < 4) ? 0 : 16384) + (c & 3) * 4096 + ldsW]);
        }
    };

    f32x4 acc[8][4];
#pragma unroll
    for (int i = 0; i < 8; ++i)
#pragma unroll
        for (int j = 0; j < 4; ++j) acc[i][j] = (f32x4){0.f, 0.f, 0.f, 0.f};

    STAGE(0, 0);
    __syncthreads();

    for (int kt = 0; kt < M_ / 64; ++kt) {
        const int bo = (kt & 1) << 15;
        const int nbo = bo ^ 32768;
        if (kt < M_ / 64 - 1) STAGE(nbo, kt + 1);

#pragma unroll
        for (int h = 0; h < 2; ++h) {                   // two K=32 halves
            const int p = (h * 4 + quad) ^ (r16 & 7);   // swizzled granule pos
            bf16x8 a[8], bbr[4];
#pragma unroll
            for (int i = 0; i < 8; ++i)
                a[i] = *(const bf16x8*)&lds[bo + (wn + i * 16 + r16) * 64 + p * 8];
#pragma unroll
            for (int j = 0; j < 4; ++j)
                bbr[j] = *(const bf16x8*)&lds[bo + 16384 + (wd + j * 16 + r16) * 64 + p * 8];
            __builtin_amdgcn_s_setprio(1);
#pragma unroll
            for (int i = 0; i < 8; ++i)
#pragma unroll
                for (int j = 0; j < 4; ++j)
                    acc[i][j] = __builtin_amdgcn_mfma_f32_16x16x32_bf16(a[i], bbr[j], acc[i][j], 0, 0, 0);
            __builtin_amdgcn_s_setprio(0);
        }
        __syncthreads();
    }

    float* ob = out + (size_t)b * N_ * D_;
#pragma unroll
    for (int i = 0; i < 8; ++i) {
        const int rbase = n0 + wn + i * 16 + quad * 4;
#pragma unroll
        for (int j = 0; j < 4; ++j) {
            const int col = d0 + wd + j * 16 + r16;
#pragma unroll
            for (int r = 0; r < 4; ++r)
                ob[(size_t)(rbase + r) * D_ + col] = acc[i][j][r];
        }
    }
}

extern "C" void kernel_launch(void* const* d_in, const int* in_sizes, int n_in,
                              void* d_out, int out_size, void* d_ws, size_t ws_size,
                              hipStream_t stream) {
    const float* x = (const float*)d_in[0];
    const float* y = (const float*)d_in[1];
    float* out = (float*)d_out;
    char* ws = (char*)d_ws;

    // Per-chunk footprint (g batches), with overlays: exactly 32g MiB.
    //   [xh 4g][xl 4g][yh 4g][yl 4g][e 16g]
    // After gemm1: xt overlays xl (dead); pT overlays yh+yl (dead).
    // xh stays ALIVE through k_tx (which reads it) -> stats in d_out tail.
    const size_t MiB = 1024 * 1024;
    int g = 8;
    while (g > 1 && (size_t)g * 32 * MiB > ws_size) g >>= 1;
    if ((size_t)g * 32 * MiB > ws_size) return;  // ws too small: clean fail (diagnostic)

    const size_t T = (size_t)g * M_ * D_ * 2;  // one split tensor (4g MiB)
    uint16_t* xh = (uint16_t*)(ws + 0 * T);
    uint16_t* xl = (uint16_t*)(ws + 1 * T);
    uint16_t* yh = (uint16_t*)(ws + 2 * T);
    uint16_t* yl = (uint16_t*)(ws + 3 * T);
    float*    e  = (float*)(ws + 4 * T);
    uint16_t* xt = xl;                          // overlays xl (dead after gemm1)
    uint16_t* pT = yh;                          // overlays yh+yl (dead after gemm1)

    // Partials + stats live in the tail of d_out: d_out is dead until gemm2,
    // and only the SAME chunk's gemm2 (after texp consumed them) covers the
    // tail; earlier chunks' gemm2 never touch it.
    const size_t pelems = (size_t)32 * g * M_;
    float* dtail = (float*)d_out + (size_t)B_ * N_ * D_;
    float* pmax = dtail - 2 * pelems;
    float* psum = pmax + pelems;
    float* mx   = dtail - 2 * pelems - 2 * (size_t)g * M_;
    float* inv  = mx + (size_t)g * M_;

    for (int c0 = 0; c0 < B_; c0 += g) {
        const float* xc = x + (size_t)c0 * M_ * D_;
        const float* yc = y + (size_t)c0 * N_ * D_;
        float* oc = out + (size_t)c0 * N_ * D_;

        hipLaunchKernelGGL(k_split, dim3((g * M_ * D_) / (256 * 4)), dim3(256), 0, stream,
                           xc, yc, xh, xl, yh, yl);
        hipLaunchKernelGGL(k_gemm1, dim3(M_ / 256, N_ / 256, g), dim3(512), 0, stream,
                           xh, xl, yh, yl, e, pmax, psum);
        hipLaunchKernelGGL(k_combine, dim3((g * M_) / 256), dim3(256), 0, stream,
                           pmax, psum, mx, inv, g * M_);
        hipLaunchKernelGGL(k_texp, dim3(M_ / 64, N_ / 64, g), dim3(256), 0, stream,
                           e, mx, inv, pT);
        hipLaunchKernelGGL(k_tx, dim3(M_ / 64, D_ / 64, g), dim3(256), 0, stream, xh, xt);
        hipLaunchKernelGGL(k_gemm2, dim3(N_ / 256, D_ / 256, g), dim3(512), 0, stream,
                           pT, xt, oc);
    }
}